// Round 1
// baseline (1373.399 us; speedup 1.0000x reference)
//
#include <hip/hip_runtime.h>

#define NN 50000      // nodes
#define NR 10         // relations (one direction)
#define R2 21         // 2*NR+1
#define NE 500000     // triples
#define NB 16384      // batch
#define HID 64

// ---------------- count kernel: histogram over col for fwd+bwd edges ----------
__global__ void count_kernel(const int* __restrict__ triples, int* __restrict__ cnt) {
    int t = blockIdx.x * blockDim.x + threadIdx.x;
    if (t >= 2 * NE) return;
    int col;
    if (t < NE) {
        int p = triples[3 * t + 1], o = triples[3 * t + 2];
        col = p * NN + o;
    } else {
        int i = t - NE;
        int s = triples[3 * i], p = triples[3 * i + 1];
        col = (p + NR) * NN + s;
    }
    atomicAdd(cnt + col, 1);
}

// ---------------- layer 1: h[dst] += val * w0[col,:]  (one wave per edge) -----
__global__ __launch_bounds__(256) void layer1_kernel(const int* __restrict__ triples,
                                                     const float* __restrict__ w0,
                                                     const int* __restrict__ cnt,
                                                     float* __restrict__ h) {
    int gid = blockIdx.x * blockDim.x + threadIdx.x;
    int w = gid >> 6;
    int lane = threadIdx.x & 63;
    if (w >= 2 * NE + NN) return;
    int dst, col; float val;
    if (w < NE) {
        int s = triples[3 * w], p = triples[3 * w + 1], o = triples[3 * w + 2];
        col = p * NN + o; dst = s; val = 1.0f / (float)cnt[col];
    } else if (w < 2 * NE) {
        int i = w - NE;
        int s = triples[3 * i], p = triples[3 * i + 1], o = triples[3 * i + 2];
        col = (p + NR) * NN + s; dst = o; val = 1.0f / (float)cnt[col];
    } else {
        int v = w - 2 * NE;
        col = 2 * NR * NN + v; dst = v; val = 1.0f;
    }
    float wv = w0[(long long)col * HID + lane];
    atomicAdd(h + dst * HID + lane, val * wv);
}

// ---------------- add b0 to h -------------------------------------------------
__global__ void bias_kernel(float* __restrict__ h, const float* __restrict__ b0) {
    int t = blockIdx.x * blockDim.x + threadIdx.x;
    if (t < NN * HID) h[t] += b0[t & 63];
}

// ---------------- layer 2: nodes[dst] += val * (h[src] @ w1[rel]) -------------
// blockIdx.y = relation rr in [0,21). Each lane register-caches w1[rr][:,lane].
// One wave per edge; waves grid-stride-scan the edge list, skipping rel mismatches.
__global__ __launch_bounds__(256) void layer2_kernel(const int* __restrict__ triples,
                                                     const float* __restrict__ h,
                                                     const float* __restrict__ w1,
                                                     const int* __restrict__ cnt,
                                                     float* __restrict__ nodes) {
    const int rr = blockIdx.y;          // 0..20
    const int lane = threadIdx.x & 63;

    float wreg[HID];
    const float* wbase = w1 + rr * HID * HID + lane;
#pragma unroll
    for (int k = 0; k < HID; ++k) wreg[k] = wbase[k * HID];

    int wave = (blockIdx.x * blockDim.x + threadIdx.x) >> 6;
    int nwaves = gridDim.x * (blockDim.x >> 6);

    if (rr == 2 * NR) {
        // self-loops: val = 1, src = dst = v
        for (int v = wave; v < NN; v += nwaves) {
            int su = __builtin_amdgcn_readfirstlane(v);
            const float* hrow = h + su * HID;
            float acc = 0.f;
#pragma unroll
            for (int k = 0; k < HID; ++k) acc += hrow[k] * wreg[k];
            atomicAdd(nodes + v * HID + lane, acc);
        }
    } else {
        const bool fwd = (rr < NR);
        const int pm = fwd ? rr : (rr - NR);
        for (int e = wave; e < NE; e += nwaves) {
            int p = triples[3 * e + 1];
            if (p != pm) continue;
            int s = triples[3 * e], o = triples[3 * e + 2];
            int src, dst, col;
            if (fwd) { src = o; dst = s; col = rr * NN + o; }
            else     { src = s; dst = o; col = rr * NN + s; }
            float val = 1.0f / (float)cnt[col];
            int su = __builtin_amdgcn_readfirstlane(src);
            const float* hrow = h + su * HID;
            float acc = 0.f;
#pragma unroll
            for (int k = 0; k < HID; ++k) acc += hrow[k] * wreg[k];
            atomicAdd(nodes + dst * HID + lane, val * acc);
        }
    }
}

// ---------------- scores: wave per batch item --------------------------------
__global__ __launch_bounds__(256) void score_kernel(const int* __restrict__ batch,
                                                    const float* __restrict__ nodes,
                                                    const float* __restrict__ b1,
                                                    const float* __restrict__ rel,
                                                    float* __restrict__ out) {
    int wave = (blockIdx.x * blockDim.x + threadIdx.x) >> 6;
    int lane = threadIdx.x & 63;
    if (wave >= NB) return;
    int si = batch[3 * wave], pi = batch[3 * wave + 1], oi = batch[3 * wave + 2];
    float a = nodes[si * HID + lane] + b1[lane];
    float b = nodes[oi * HID + lane] + b1[lane];
    float v = a * rel[pi * HID + lane] * b;
#pragma unroll
    for (int off = 32; off; off >>= 1) v += __shfl_down(v, off, 64);
    if (lane == 0) out[wave] = v;
}

extern "C" void kernel_launch(void* const* d_in, const int* in_sizes, int n_in,
                              void* d_out, int out_size, void* d_ws, size_t ws_size,
                              hipStream_t stream) {
    const int*   batch   = (const int*)d_in[0];
    const int*   triples = (const int*)d_in[1];
    const float* w0      = (const float*)d_in[2];
    const float* b0      = (const float*)d_in[3];
    const float* w1      = (const float*)d_in[4];
    const float* b1      = (const float*)d_in[5];
    const float* rel     = (const float*)d_in[6];
    float* out = (float*)d_out;

    char* ws = (char*)d_ws;
    int*   cnt   = (int*)ws;                                  // 2*NR*NN ints  = 4.0 MB
    float* h     = (float*)(ws + (size_t)2 * NR * NN * 4);    // NN*HID floats = 12.8 MB
    float* nodes = h + (size_t)NN * HID;                      // NN*HID floats = 12.8 MB

    size_t zero_bytes = (size_t)2 * NR * NN * 4 + 2 * (size_t)NN * HID * 4;
    hipMemsetAsync(d_ws, 0, zero_bytes, stream);

    count_kernel<<<(2 * NE + 255) / 256, 256, 0, stream>>>(triples, cnt);

    int tot_edges = 2 * NE + NN;                              // 1,050,000 waves
    int l1_blocks = (tot_edges * 64 + 255) / 256;             // 262,500
    layer1_kernel<<<l1_blocks, 256, 0, stream>>>(triples, w0, cnt, h);

    bias_kernel<<<(NN * HID + 255) / 256, 256, 0, stream>>>(h, b0);

    dim3 l2grid(256, R2);
    layer2_kernel<<<l2grid, 256, 0, stream>>>(triples, h, w1, cnt, nodes);

    score_kernel<<<(NB * 64 + 255) / 256, 256, 0, stream>>>(batch, nodes, b1, rel, out);
}